// Round 7
// baseline (187.847 us; speedup 1.0000x reference)
//
#include <hip/hip_runtime.h>
#include <cmath>

#define NC 6
#define CF 64
#define HH 88
#define WW 160
#define NPIX 14080     // 88*160
#define NVOX 200000
#define VPRE 64
#define VB 128         // voxels per prep block
#define NTH 512        // 8 waves
#define NWV 8

typedef unsigned int u32;

// ws layout (bytes)
#define FEATT_BYTES  (6u * 64u * 14080u * 4u)            // 21,626,880
#define REC1_OFF     FEATT_BYTES                          // 200000 * float4
#define REC1_BYTES   (200000u * 16u)
#define REC2_OFF     (REC1_OFF + REC1_BYTES)              // 100000 entries * 2 float4
#define REC2_BYTES   (200000u * 16u)
#define CNT_OFF      (REC2_OFF + REC2_BYTES)
#define WS_NEED      (CNT_OFF + 16u)

// ---------------- zero-fill output + counters ----------------
__global__ __launch_bounds__(256) void zfill(float4* __restrict__ out, int n4,
                                             int* __restrict__ cnt) {
    int i = blockIdx.x * 256 + threadIdx.x;
    int stride = gridDim.x * 256;
    for (; i < n4; i += stride) out[i] = make_float4(0.f, 0.f, 0.f, 0.f);
    if (cnt && blockIdx.x == 0 && threadIdx.x < 2) cnt[threadIdx.x] = 0;
}

// ---------------- transpose [6][64][H*W] -> [6][H*W][64] (f32) ----------------
__global__ __launch_bounds__(256) void transpose_feats(const float* __restrict__ in,
                                                       float* __restrict__ out) {
    __shared__ float tile[64 * 65];
    int blk = blockIdx.x;            // 6 * 220
    int c = blk / 220;
    int p0 = (blk - c * 220) * 64;
    int tid = threadIdx.x;
    int lane = tid & 63;
    int quad = tid >> 6;
    for (int r = quad; r < 64; r += 4)
        tile[r * 65 + lane] = in[(c * 64 + r) * NPIX + p0 + lane];
    __syncthreads();
    for (int r = quad; r < 64; r += 4)
        out[((c * NPIX) + p0 + r) * 64 + lane] = tile[lane * 65 + r];
}

__device__ __forceinline__ float elu1(float x) { return x > 0.0f ? x : expm1f(x); }

// bilinear gather: voxel uniform across wave, lane = channel. Math identical to r3/r5/r6.
__device__ __forceinline__ float gather_bilin(const float* __restrict__ fsrc, int useT,
                                              int lane, int cam, float x, float y) {
    float x0f = floorf(x), y0f = floorf(y);
    float wx1 = x - x0f, wx0 = 1.0f - wx1;
    float wy1 = y - y0f, wy0 = 1.0f - wy1;
    float x1f = x0f + 1.0f, y1f = y0f + 1.0f;
    float bx0 = (x0f >= 0.0f && x0f <= 159.0f) ? 1.0f : 0.0f;
    float bx1 = (x1f >= 0.0f && x1f <= 159.0f) ? 1.0f : 0.0f;
    float by0 = (y0f >= 0.0f && y0f <= 87.0f) ? 1.0f : 0.0f;
    float by1 = (y1f >= 0.0f && y1f <= 87.0f) ? 1.0f : 0.0f;
    int ix0 = (int)fminf(fmaxf(x0f, 0.0f), 159.0f);
    int ix1 = (int)fminf(fmaxf(x1f, 0.0f), 159.0f);
    int iy0 = (int)fminf(fmaxf(y0f, 0.0f), 87.0f);
    int iy1 = (int)fminf(fmaxf(y1f, 0.0f), 87.0f);
    int A = useT ? 64 : 1;
    int Boff = useT ? (cam * NPIX * 64 + lane) : ((cam * 64 + lane) * NPIX);
    float v00 = fsrc[(iy0 * WW + ix0) * A + Boff];
    float v01 = fsrc[(iy1 * WW + ix0) * A + Boff];
    float v10 = fsrc[(iy0 * WW + ix1) * A + Boff];
    float v11 = fsrc[(iy1 * WW + ix1) * A + Boff];
    float fv;                                        // reference corner order
    fv  = (wx0 * wy0 * bx0 * by0) * v00;
    fv += (wx0 * wy1 * bx0 * by1) * v01;
    fv += (wx1 * wy0 * bx1 * by0) * v10;
    fv += (wx1 * wy1 * bx1 * by1) * v11;
    return fv;
}

// 8-output FMA step over 4 channels, weights via wave-uniform scalar loads
#define FMA8_STEP(W0,W1,W2,W3,W4,W5,W6,W7,CG,F0,F1,F2,F3) \
    a0 += W0[CG]*F0; a0 += W0[CG+1]*F1; a0 += W0[CG+2]*F2; a0 += W0[CG+3]*F3; \
    a1 += W1[CG]*F0; a1 += W1[CG+1]*F1; a1 += W1[CG+2]*F2; a1 += W1[CG+3]*F3; \
    a2 += W2[CG]*F0; a2 += W2[CG+1]*F1; a2 += W2[CG+2]*F2; a2 += W2[CG+3]*F3; \
    a3 += W3[CG]*F0; a3 += W3[CG+1]*F1; a3 += W3[CG+2]*F2; a3 += W3[CG+3]*F3; \
    a4 += W4[CG]*F0; a4 += W4[CG+1]*F1; a4 += W4[CG+2]*F2; a4 += W4[CG+3]*F3; \
    a5 += W5[CG]*F0; a5 += W5[CG+1]*F1; a5 += W5[CG+2]*F2; a5 += W5[CG+3]*F3; \
    a6 += W6[CG]*F0; a6 += W6[CG+1]*F1; a6 += W6[CG+2]*F2; a6 += W6[CG+3]*F3; \
    a7 += W7[CG]*F0; a7 += W7[CG+1]*F1; a7 += W7[CG+2]*F2; a7 += W7[CG+3]*F3;

// geometry body shared by prep and fallback — EXACT r3/r5/r6 arithmetic
#define GEOMETRY_PHASE(SPAIR)                                                  \
    for (int p = tid; p < NC * VB; p += NTH) {                                 \
        _Pragma("clang fp contract(off)")                                      \
        int cam = p >> 7;                                                      \
        int v = p & (VB - 1);                                                  \
        int n = base + v;                                                      \
        if (n < NVOX) {                                                        \
            int xi = n % 100;                                                  \
            int t = n / 100;                                                   \
            int yi = t % 100;                                                  \
            int zi = t / 100;                                                  \
            float X = -50.0f + (float)xi;                                      \
            float Y = -50.0f + (float)yi;                                      \
            float Z = -15.0f + 1.5f * (float)zi;                               \
            const float* E = s_ext + cam * 12;                                 \
            const float* Kk = s_K + cam * 9;                                   \
            float vl0 = E[0]*X + E[1]*Y + E[2]*Z + E[3];                       \
            float vl1 = E[4]*X + E[5]*Y + E[6]*Z + E[7];                       \
            float vl2 = E[8]*X + E[9]*Y + E[10]*Z + E[11];                     \
            float c0 = Kk[0]*vl0 + Kk[1]*vl1 + Kk[2]*vl2;                      \
            float c1 = Kk[3]*vl0 + Kk[4]*vl1 + Kk[5]*vl2;                      \
            float c2 = Kk[6]*vl0 + Kk[7]*vl1 + Kk[8]*vl2;                      \
            float pz = c2 + 1e-8f;                                             \
            float px = c0 / pz;                                                \
            float py = c1 / pz;                                                \
            float gx = (px / 159.0f - 0.5f) * 2.0f;                            \
            float gy = (py / 87.0f - 0.5f) * 2.0f;                             \
            float x = ((gx + 1.0f) * 0.5f) * 159.0f;                           \
            float y = ((gy + 1.0f) * 0.5f) * 87.0f;                            \
            float xr = rintf(x), yr = rintf(y);                                \
            bool nv = (xr >= 0.0f) && (xr <= 159.0f) && (yr >= 0.0f) && (yr <= 87.0f); \
            float mval = 0.0f;                                                 \
            if (nv) mval = mask[(cam * HH + (int)yr) * WW + (int)xr];          \
            bool ok = (mval > 0.5f) && (vl2 > 0.0f) &&                         \
                      !((gx > 1.0f) || (gx < -1.0f) || (gy > 1.0f) || (gy < -1.0f)); \
            SPAIR[cam * VB + v] = make_float4(x, y, vl2, ok ? 1.0f : 0.0f);    \
        } else {                                                               \
            SPAIR[cam * VB + v] = make_float4(0.0f, 0.0f, 0.0f, 0.0f);         \
        }                                                                      \
    }

// ---------------- kernel A: geometry + compaction -> global records ----------------
__global__ __launch_bounds__(NTH) void vox_prep(
    const float* __restrict__ mask,
    const float* __restrict__ Kg,
    const float* __restrict__ ext,
    float4* __restrict__ rec1,       // [<=200000] {x,y,z,meta}
    float4* __restrict__ rec2,       // [<=100000][2] {x,y,z,meta}
    int* __restrict__ cnt)           // [2] pre-zeroed
{
    __shared__ float s_ext[72];
    __shared__ float s_K[54];
    __shared__ __align__(16) float4 s_pair[NC * VB];
    __shared__ u32 s_list1[VB], s_list2[VB];
    __shared__ int s_n1, s_n2, s_base1, s_base2;

    int tid = threadIdx.x;
    int base = blockIdx.x * VB;

    if (tid == 0) { s_n1 = 0; s_n2 = 0; }
    if (tid >= 64 && tid < 136) {
        int i = tid - 64;
        s_ext[i] = ext[(i / 12) * 16 + (i % 12)];
    }
    if (tid >= 192 && tid < 246) {
        int i = tid - 192; int cam = i / 9; int e = i - cam * 9;
        s_K[i] = Kg[cam * 16 + (e / 3) * 4 + (e % 3)];
    }
    __syncthreads();

    GEOMETRY_PHASE(s_pair)
    __syncthreads();

    if (tid < VB) {
        int v = tid;
        const float* pw = (const float*)s_pair;
        int cnt_ = 0, cam0 = 0, cam1 = 0;
        #pragma unroll
        for (int c = 0; c < NC; ++c) {
            float w = pw[(c * VB + v) * 4 + 3];
            if (w != 0.0f) { if (cnt_ == 0) cam0 = c; else if (cnt_ == 1) cam1 = c; ++cnt_; }
        }
        if (cnt_ == 1) {
            int s = atomicAdd(&s_n1, 1);
            s_list1[s] = (u32)(v | (cam0 << 8));
        } else if (cnt_ == 2) {
            int s = atomicAdd(&s_n2, 1);
            s_list2[s] = (u32)(v | (cam0 << 8) | (cam1 << 12));
        }
    }
    __syncthreads();
    if (tid == 0) s_base1 = atomicAdd(&cnt[0], s_n1);
    if (tid == 1) s_base2 = atomicAdd(&cnt[1], s_n2);
    __syncthreads();

    int n1 = s_n1, n2 = s_n2;
    if (tid < n1) {
        u32 ent = s_list1[tid];
        int v = ent & 127, c = (ent >> 8) & 7;
        float4 pd = s_pair[c * VB + v];
        int meta = ((base + v) << 3) | c;
        rec1[s_base1 + tid] = make_float4(pd.x, pd.y, pd.z, __int_as_float(meta));
    }
    if (tid >= 256 && tid - 256 < n2) {
        int j = tid - 256;
        u32 ent = s_list2[j];
        int v = ent & 127;
        int c0 = (ent >> 8) & 15, c1 = (ent >> 12) & 15;
        float4 p0 = s_pair[c0 * VB + v];
        float4 p1 = s_pair[c1 * VB + v];
        int vox = base + v;
        rec2[2 * (s_base2 + j) + 0] = make_float4(p0.x, p0.y, p0.z, __int_as_float((vox << 3) | c0));
        rec2[2 * (s_base2 + j) + 1] = make_float4(p1.x, p1.y, p1.z, __int_as_float((vox << 3) | c1));
    }
}

// ---------------- kernel B: full-tile gather + matvec ----------------
__global__ __launch_bounds__(NTH) void vox_mv(
    const float* __restrict__ feats,
    const float* __restrict__ featT,
    const float4* __restrict__ rec1,
    const float4* __restrict__ rec2,
    const int* __restrict__ cnt,
    const float* __restrict__ wno,   // [64][65]
    const float* __restrict__ bno,   // [64]
    const float* __restrict__ wo,    // [64][130]
    const float* __restrict__ bo,    // [64]
    float* __restrict__ outp,        // [64][200000], pre-zeroed
    int useT)
{
    __shared__ float s_F[65 * 66];   // [channel][entry], stride 66
    __shared__ int s_vox[64];

    int tid = threadIdx.x;
    int lane = tid & 63;
    int wv = tid >> 6;               // 0..7
    int c1 = cnt[0], c2 = cnt[1];
    int nt1 = (c1 + 63) >> 6, nt2 = (c2 + 63) >> 6;
    int nt = nt1 + nt2;

    const float* fsrc = useT ? featT : feats;
    int wvu = __builtin_amdgcn_readfirstlane(wv);
    int obase = wvu * 8;
    const float* w0n = wno + (obase + 0) * 65;
    const float* w1n = wno + (obase + 1) * 65;
    const float* w2n = wno + (obase + 2) * 65;
    const float* w3n = wno + (obase + 3) * 65;
    const float* w4n = wno + (obase + 4) * 65;
    const float* w5n = wno + (obase + 5) * 65;
    const float* w6n = wno + (obase + 6) * 65;
    const float* w7n = wno + (obase + 7) * 65;
    const float* w0o = wo + (obase + 0) * 130;
    const float* w1o = wo + (obase + 1) * 130;
    const float* w2o = wo + (obase + 2) * 130;
    const float* w3o = wo + (obase + 3) * 130;
    const float* w4o = wo + (obase + 4) * 130;
    const float* w5o = wo + (obase + 5) * 130;
    const float* w6o = wo + (obase + 6) * 130;
    const float* w7o = wo + (obase + 7) * 130;

    for (int t = blockIdx.x; t < nt; t += gridDim.x) {
        if (t < nt1) {
            // -------- count==1 tile --------
            int e0 = t << 6;
            int tl = min(64, c1 - e0);
            for (int e = wv; e < tl; e += NWV) {
                float4 r = rec1[e0 + e];                    // wave-uniform
                int meta = __float_as_int(r.w);
                int cam = meta & 7;
                float fv = gather_bilin(fsrc, useT, lane, cam, r.x, r.y);
                s_F[lane * 66 + e] = fv;
                if (lane == 0) { s_F[64 * 66 + e] = r.z / 100.0f; s_vox[e] = meta >> 3; }
            }
            __syncthreads();
            float a0 = bno[obase + 0], a1 = bno[obase + 1], a2 = bno[obase + 2], a3 = bno[obase + 3];
            float a4 = bno[obase + 4], a5 = bno[obase + 5], a6 = bno[obase + 6], a7 = bno[obase + 7];
            for (int cg = 0; cg < 64; cg += 4) {
                float f0 = s_F[(cg + 0) * 66 + lane];
                float f1 = s_F[(cg + 1) * 66 + lane];
                float f2 = s_F[(cg + 2) * 66 + lane];
                float f3 = s_F[(cg + 3) * 66 + lane];
                FMA8_STEP(w0n, w1n, w2n, w3n, w4n, w5n, w6n, w7n, cg, f0, f1, f2, f3)
            }
            float fd = s_F[64 * 66 + lane];
            a0 += w0n[64] * fd; a1 += w1n[64] * fd; a2 += w2n[64] * fd; a3 += w3n[64] * fd;
            a4 += w4n[64] * fd; a5 += w5n[64] * fd; a6 += w6n[64] * fd; a7 += w7n[64] * fd;
            if (lane < tl) {
                size_t col = (size_t)s_vox[lane];
                outp[(size_t)(obase + 0) * NVOX + col] = elu1(a0);
                outp[(size_t)(obase + 1) * NVOX + col] = elu1(a1);
                outp[(size_t)(obase + 2) * NVOX + col] = elu1(a2);
                outp[(size_t)(obase + 3) * NVOX + col] = elu1(a3);
                outp[(size_t)(obase + 4) * NVOX + col] = elu1(a4);
                outp[(size_t)(obase + 5) * NVOX + col] = elu1(a5);
                outp[(size_t)(obase + 6) * NVOX + col] = elu1(a6);
                outp[(size_t)(obase + 7) * NVOX + col] = elu1(a7);
            }
            __syncthreads();
        } else {
            // -------- count==2 tile: two passes over the 65-row F tile --------
            int e0 = (t - nt1) << 6;
            int tl = min(64, c2 - e0);
            for (int e = wv; e < tl; e += NWV) {            // pass A gather: cams {0,3,4}
                float4 r0 = rec2[2 * (e0 + e) + 0];
                float4 r1 = rec2[2 * (e0 + e) + 1];
                int m0 = __float_as_int(r0.w), m1 = __float_as_int(r1.w);
                int ca = m0 & 7, cb = m1 & 7;
                float fg = 0.0f, dd = 0.0f;
                if (!(ca == 1 || ca == 2 || ca == 5)) {
                    fg += gather_bilin(fsrc, useT, lane, ca, r0.x, r0.y);
                    dd += r0.z / 100.0f;
                }
                if (!(cb == 1 || cb == 2 || cb == 5)) {
                    fg += gather_bilin(fsrc, useT, lane, cb, r1.x, r1.y);
                    dd += r1.z / 100.0f;
                }
                s_F[lane * 66 + e] = fg;
                if (lane == 0) { s_F[64 * 66 + e] = dd; s_vox[e] = m0 >> 3; }
            }
            __syncthreads();
            float a0 = bo[obase + 0], a1 = bo[obase + 1], a2 = bo[obase + 2], a3 = bo[obase + 3];
            float a4 = bo[obase + 4], a5 = bo[obase + 5], a6 = bo[obase + 6], a7 = bo[obase + 7];
            for (int cg = 0; cg < 64; cg += 4) {            // pass A compute: cols 0..64
                float f0 = s_F[(cg + 0) * 66 + lane];
                float f1 = s_F[(cg + 1) * 66 + lane];
                float f2 = s_F[(cg + 2) * 66 + lane];
                float f3 = s_F[(cg + 3) * 66 + lane];
                FMA8_STEP(w0o, w1o, w2o, w3o, w4o, w5o, w6o, w7o, cg, f0, f1, f2, f3)
            }
            {
                float fd = s_F[64 * 66 + lane];
                a0 += w0o[64] * fd; a1 += w1o[64] * fd; a2 += w2o[64] * fd; a3 += w3o[64] * fd;
                a4 += w4o[64] * fd; a5 += w5o[64] * fd; a6 += w6o[64] * fd; a7 += w7o[64] * fd;
            }
            __syncthreads();
            for (int e = wv; e < tl; e += NWV) {            // pass B gather: cams {1,2,5}
                float4 r0 = rec2[2 * (e0 + e) + 0];
                float4 r1 = rec2[2 * (e0 + e) + 1];
                int m0 = __float_as_int(r0.w), m1 = __float_as_int(r1.w);
                int ca = m0 & 7, cb = m1 & 7;
                float fg = 0.0f, dd = 0.0f;
                if (ca == 1 || ca == 2 || ca == 5) {
                    fg += gather_bilin(fsrc, useT, lane, ca, r0.x, r0.y);
                    dd += r0.z / 100.0f;
                }
                if (cb == 1 || cb == 2 || cb == 5) {
                    fg += gather_bilin(fsrc, useT, lane, cb, r1.x, r1.y);
                    dd += r1.z / 100.0f;
                }
                s_F[lane * 66 + e] = fg;
                if (lane == 0) s_F[64 * 66 + e] = dd;
            }
            __syncthreads();
            for (int cg = 0; cg < 64; cg += 4) {            // pass B compute: cols 65..129
                float f0 = s_F[(cg + 0) * 66 + lane];
                float f1 = s_F[(cg + 1) * 66 + lane];
                float f2 = s_F[(cg + 2) * 66 + lane];
                float f3 = s_F[(cg + 3) * 66 + lane];
                int cgo = cg + 65;
                FMA8_STEP(w0o, w1o, w2o, w3o, w4o, w5o, w6o, w7o, cgo, f0, f1, f2, f3)
            }
            {
                float fd = s_F[64 * 66 + lane];
                a0 += w0o[129] * fd; a1 += w1o[129] * fd; a2 += w2o[129] * fd; a3 += w3o[129] * fd;
                a4 += w4o[129] * fd; a5 += w5o[129] * fd; a6 += w6o[129] * fd; a7 += w7o[129] * fd;
            }
            if (lane < tl) {
                size_t col = (size_t)s_vox[lane];
                outp[(size_t)(obase + 0) * NVOX + col] = elu1(a0);
                outp[(size_t)(obase + 1) * NVOX + col] = elu1(a1);
                outp[(size_t)(obase + 2) * NVOX + col] = elu1(a2);
                outp[(size_t)(obase + 3) * NVOX + col] = elu1(a3);
                outp[(size_t)(obase + 4) * NVOX + col] = elu1(a4);
                outp[(size_t)(obase + 5) * NVOX + col] = elu1(a5);
                outp[(size_t)(obase + 6) * NVOX + col] = elu1(a6);
                outp[(size_t)(obase + 7) * NVOX + col] = elu1(a7);
            }
            __syncthreads();
        }
    }
}

// ---------------- fallback monolith (r6, proven) for small ws ----------------
__global__ __launch_bounds__(NTH, 4) void vox_main(
    const float* __restrict__ feats,
    const float* __restrict__ featT,
    const float* __restrict__ mask,
    const float* __restrict__ Kg,
    const float* __restrict__ ext,
    const float* __restrict__ wno,
    const float* __restrict__ bno,
    const float* __restrict__ wo,
    const float* __restrict__ bo,
    float* __restrict__ outp,
    int useT)
{
    __shared__ float s_ext[72];
    __shared__ float s_K[54];
    __shared__ __align__(16) float4 s_pair[NC * VB];
    __shared__ float s_F[65 * 66];
    __shared__ u32 s_list1[VB], s_list2[VB];
    __shared__ int s_n1, s_n2;

    int tid = threadIdx.x;
    int lane = tid & 63;
    int wv = tid >> 6;
    int base = blockIdx.x * VB;

    if (tid == 0) { s_n1 = 0; s_n2 = 0; }
    if (tid >= 64 && tid < 136) {
        int i = tid - 64;
        s_ext[i] = ext[(i / 12) * 16 + (i % 12)];
    }
    if (tid >= 192 && tid < 246) {
        int i = tid - 192; int cam = i / 9; int e = i - cam * 9;
        s_K[i] = Kg[cam * 16 + (e / 3) * 4 + (e % 3)];
    }
    __syncthreads();

    GEOMETRY_PHASE(s_pair)
    __syncthreads();

    if (tid < VB) {
        int v = tid;
        const float* pw = (const float*)s_pair;
        int cnt = 0, cam0 = 0, cam1 = 0;
        #pragma unroll
        for (int c = 0; c < NC; ++c) {
            float w = pw[(c * VB + v) * 4 + 3];
            if (w != 0.0f) { if (cnt == 0) cam0 = c; else if (cnt == 1) cam1 = c; ++cnt; }
        }
        if (cnt == 1) {
            int s = atomicAdd(&s_n1, 1);
            s_list1[s] = (u32)(v | (cam0 << 8));
        } else if (cnt == 2) {
            int s = atomicAdd(&s_n2, 1);
            s_list2[s] = (u32)(v | (cam0 << 8) | (cam1 << 12));
        }
    }
    __syncthreads();

    int n1 = s_n1, n2 = s_n2;
    const float* fsrc = useT ? featT : feats;
    int wvu = __builtin_amdgcn_readfirstlane(wv);
    int obase = wvu * 8;
    const float* w0n = wno + (obase + 0) * 65;
    const float* w1n = wno + (obase + 1) * 65;
    const float* w2n = wno + (obase + 2) * 65;
    const float* w3n = wno + (obase + 3) * 65;
    const float* w4n = wno + (obase + 4) * 65;
    const float* w5n = wno + (obase + 5) * 65;
    const float* w6n = wno + (obase + 6) * 65;
    const float* w7n = wno + (obase + 7) * 65;
    const float* w0o = wo + (obase + 0) * 130;
    const float* w1o = wo + (obase + 1) * 130;
    const float* w2o = wo + (obase + 2) * 130;
    const float* w3o = wo + (obase + 3) * 130;
    const float* w4o = wo + (obase + 4) * 130;
    const float* w5o = wo + (obase + 5) * 130;
    const float* w6o = wo + (obase + 6) * 130;
    const float* w7o = wo + (obase + 7) * 130;

    for (int t0 = 0; t0 < n1; t0 += 64) {
        int tl = min(64, n1 - t0);
        for (int e = wv; e < tl; e += NWV) {
            u32 ent = s_list1[t0 + e];
            int v = ent & 127, c = (ent >> 8) & 7;
            float4 pd = s_pair[c * VB + v];
            float fv = gather_bilin(fsrc, useT, lane, c, pd.x, pd.y);
            s_F[lane * 66 + e] = fv;
            if (lane == 0) s_F[64 * 66 + e] = pd.z / 100.0f;
        }
        __syncthreads();
        float a0 = bno[obase + 0], a1 = bno[obase + 1], a2 = bno[obase + 2], a3 = bno[obase + 3];
        float a4 = bno[obase + 4], a5 = bno[obase + 5], a6 = bno[obase + 6], a7 = bno[obase + 7];
        for (int cg = 0; cg < 64; cg += 4) {
            float f0 = s_F[(cg + 0) * 66 + lane];
            float f1 = s_F[(cg + 1) * 66 + lane];
            float f2 = s_F[(cg + 2) * 66 + lane];
            float f3 = s_F[(cg + 3) * 66 + lane];
            FMA8_STEP(w0n, w1n, w2n, w3n, w4n, w5n, w6n, w7n, cg, f0, f1, f2, f3)
        }
        float fd = s_F[64 * 66 + lane];
        a0 += w0n[64] * fd; a1 += w1n[64] * fd; a2 += w2n[64] * fd; a3 += w3n[64] * fd;
        a4 += w4n[64] * fd; a5 += w5n[64] * fd; a6 += w6n[64] * fd; a7 += w7n[64] * fd;
        if (lane < tl) {
            size_t col = (size_t)(base + (int)(s_list1[t0 + lane] & 127));
            outp[(size_t)(obase + 0) * NVOX + col] = elu1(a0);
            outp[(size_t)(obase + 1) * NVOX + col] = elu1(a1);
            outp[(size_t)(obase + 2) * NVOX + col] = elu1(a2);
            outp[(size_t)(obase + 3) * NVOX + col] = elu1(a3);
            outp[(size_t)(obase + 4) * NVOX + col] = elu1(a4);
            outp[(size_t)(obase + 5) * NVOX + col] = elu1(a5);
            outp[(size_t)(obase + 6) * NVOX + col] = elu1(a6);
            outp[(size_t)(obase + 7) * NVOX + col] = elu1(a7);
        }
        __syncthreads();
    }

    for (int t0 = 0; t0 < n2; t0 += 64) {
        int tl = min(64, n2 - t0);
        for (int e = wv; e < tl; e += NWV) {
            u32 ent = s_list2[t0 + e];
            int v = ent & 127;
            int c0 = (ent >> 8) & 15, c1 = (ent >> 12) & 15;
            float fg = 0.0f, dd = 0.0f;
            if (!(c0 == 1 || c0 == 2 || c0 == 5)) {
                float4 pd = s_pair[c0 * VB + v];
                fg += gather_bilin(fsrc, useT, lane, c0, pd.x, pd.y);
                dd += pd.z / 100.0f;
            }
            if (!(c1 == 1 || c1 == 2 || c1 == 5)) {
                float4 pd = s_pair[c1 * VB + v];
                fg += gather_bilin(fsrc, useT, lane, c1, pd.x, pd.y);
                dd += pd.z / 100.0f;
            }
            s_F[lane * 66 + e] = fg;
            if (lane == 0) s_F[64 * 66 + e] = dd;
        }
        __syncthreads();
        float a0 = bo[obase + 0], a1 = bo[obase + 1], a2 = bo[obase + 2], a3 = bo[obase + 3];
        float a4 = bo[obase + 4], a5 = bo[obase + 5], a6 = bo[obase + 6], a7 = bo[obase + 7];
        for (int cg = 0; cg < 64; cg += 4) {
            float f0 = s_F[(cg + 0) * 66 + lane];
            float f1 = s_F[(cg + 1) * 66 + lane];
            float f2 = s_F[(cg + 2) * 66 + lane];
            float f3 = s_F[(cg + 3) * 66 + lane];
            FMA8_STEP(w0o, w1o, w2o, w3o, w4o, w5o, w6o, w7o, cg, f0, f1, f2, f3)
        }
        {
            float fd = s_F[64 * 66 + lane];
            a0 += w0o[64] * fd; a1 += w1o[64] * fd; a2 += w2o[64] * fd; a3 += w3o[64] * fd;
            a4 += w4o[64] * fd; a5 += w5o[64] * fd; a6 += w6o[64] * fd; a7 += w7o[64] * fd;
        }
        __syncthreads();
        for (int e = wv; e < tl; e += NWV) {
            u32 ent = s_list2[t0 + e];
            int v = ent & 127;
            int c0 = (ent >> 8) & 15, c1 = (ent >> 12) & 15;
            float fg = 0.0f, dd = 0.0f;
            if (c0 == 1 || c0 == 2 || c0 == 5) {
                float4 pd = s_pair[c0 * VB + v];
                fg += gather_bilin(fsrc, useT, lane, c0, pd.x, pd.y);
                dd += pd.z / 100.0f;
            }
            if (c1 == 1 || c1 == 2 || c1 == 5) {
                float4 pd = s_pair[c1 * VB + v];
                fg += gather_bilin(fsrc, useT, lane, c1, pd.x, pd.y);
                dd += pd.z / 100.0f;
            }
            s_F[lane * 66 + e] = fg;
            if (lane == 0) s_F[64 * 66 + e] = dd;
        }
        __syncthreads();
        for (int cg = 0; cg < 64; cg += 4) {
            float f0 = s_F[(cg + 0) * 66 + lane];
            float f1 = s_F[(cg + 1) * 66 + lane];
            float f2 = s_F[(cg + 2) * 66 + lane];
            float f3 = s_F[(cg + 3) * 66 + lane];
            int cgo = cg + 65;
            FMA8_STEP(w0o, w1o, w2o, w3o, w4o, w5o, w6o, w7o, cgo, f0, f1, f2, f3)
        }
        {
            float fd = s_F[64 * 66 + lane];
            a0 += w0o[129] * fd; a1 += w1o[129] * fd; a2 += w2o[129] * fd; a3 += w3o[129] * fd;
            a4 += w4o[129] * fd; a5 += w5o[129] * fd; a6 += w6o[129] * fd; a7 += w7o[129] * fd;
        }
        if (lane < tl) {
            size_t col = (size_t)(base + (int)(s_list2[t0 + lane] & 127));
            outp[(size_t)(obase + 0) * NVOX + col] = elu1(a0);
            outp[(size_t)(obase + 1) * NVOX + col] = elu1(a1);
            outp[(size_t)(obase + 2) * NVOX + col] = elu1(a2);
            outp[(size_t)(obase + 3) * NVOX + col] = elu1(a3);
            outp[(size_t)(obase + 4) * NVOX + col] = elu1(a4);
            outp[(size_t)(obase + 5) * NVOX + col] = elu1(a5);
            outp[(size_t)(obase + 6) * NVOX + col] = elu1(a6);
            outp[(size_t)(obase + 7) * NVOX + col] = elu1(a7);
        }
        __syncthreads();
    }
}

extern "C" void kernel_launch(void* const* d_in, const int* in_sizes, int n_in,
                              void* d_out, int out_size, void* d_ws, size_t ws_size,
                              hipStream_t stream) {
    const float* feats = (const float*)d_in[0];
    const float* mask  = (const float*)d_in[1];
    const float* Kg    = (const float*)d_in[2];
    const float* ext   = (const float*)d_in[3];
    const float* wno   = (const float*)d_in[4];
    const float* bno   = (const float*)d_in[5];
    const float* wo    = (const float*)d_in[6];
    const float* bo    = (const float*)d_in[7];
    float* outp = (float*)d_out;
    char* wsb = (char*)d_ws;
    float* featT = (float*)wsb;

    int useT = (ws_size >= (size_t)FEATT_BYTES) ? 1 : 0;
    int full = (ws_size >= (size_t)WS_NEED) ? 1 : 0;       // constant across calls
    int nblk = (NVOX + VB - 1) / VB;                        // 1563
    int n4 = out_size / 4;

    if (full) {
        float4* rec1 = (float4*)(wsb + REC1_OFF);
        float4* rec2 = (float4*)(wsb + REC2_OFF);
        int* cnt = (int*)(wsb + CNT_OFF);
        zfill<<<2048, 256, 0, stream>>>((float4*)d_out, n4, cnt);
        transpose_feats<<<NC * 220, 256, 0, stream>>>(feats, featT);
        vox_prep<<<nblk, NTH, 0, stream>>>(mask, Kg, ext, rec1, rec2, cnt);
        vox_mv<<<1024, NTH, 0, stream>>>(feats, featT, rec1, rec2, cnt,
                                         wno, bno, wo, bo, outp, useT);
    } else {
        zfill<<<2048, 256, 0, stream>>>((float4*)d_out, n4, (int*)nullptr);
        if (useT) transpose_feats<<<NC * 220, 256, 0, stream>>>(feats, featT);
        vox_main<<<nblk, NTH, 0, stream>>>(feats, featT, mask, Kg, ext,
                                           wno, bno, wo, bo, outp, useT);
    }
}

// Round 8
// 177.798 us; speedup vs baseline: 1.0565x; 1.0565x over previous
//
#include <hip/hip_runtime.h>
#include <cmath>

#define NC 6
#define CF 64
#define HH 88
#define WW 160
#define NPIX 14080     // 88*160
#define NVOX 200000
#define VPRE 64
#define VB 512         // voxels per block (thread = voxel)
#define NTH 512        // 8 waves
#define NWV 8

typedef unsigned int u32;

#define FEATT_BYTES  (6u * 64u * 14080u * 4u)            // 21,626,880

// ---------------- transpose [6][64][H*W] -> [6][H*W][64] (f32) ----------------
__global__ __launch_bounds__(256) void transpose_feats(const float* __restrict__ in,
                                                       float* __restrict__ out) {
    __shared__ float tile[64 * 65];
    int blk = blockIdx.x;            // 6 * 220
    int c = blk / 220;
    int p0 = (blk - c * 220) * 64;
    int tid = threadIdx.x;
    int lane = tid & 63;
    int quad = tid >> 6;
    for (int r = quad; r < 64; r += 4)
        tile[r * 65 + lane] = in[(c * 64 + r) * NPIX + p0 + lane];
    __syncthreads();
    for (int r = quad; r < 64; r += 4)
        out[((c * NPIX) + p0 + r) * 64 + lane] = tile[lane * 65 + r];
}

__device__ __forceinline__ float elu1(float x) { return x > 0.0f ? x : expm1f(x); }

// bilinear gather: voxel uniform across wave, lane = channel. Math identical to r3..r7.
__device__ __forceinline__ float gather_bilin(const float* __restrict__ fsrc, int useT,
                                              int lane, int cam, float x, float y) {
    float x0f = floorf(x), y0f = floorf(y);
    float wx1 = x - x0f, wx0 = 1.0f - wx1;
    float wy1 = y - y0f, wy0 = 1.0f - wy1;
    float x1f = x0f + 1.0f, y1f = y0f + 1.0f;
    float bx0 = (x0f >= 0.0f && x0f <= 159.0f) ? 1.0f : 0.0f;
    float bx1 = (x1f >= 0.0f && x1f <= 159.0f) ? 1.0f : 0.0f;
    float by0 = (y0f >= 0.0f && y0f <= 87.0f) ? 1.0f : 0.0f;
    float by1 = (y1f >= 0.0f && y1f <= 87.0f) ? 1.0f : 0.0f;
    int ix0 = (int)fminf(fmaxf(x0f, 0.0f), 159.0f);
    int ix1 = (int)fminf(fmaxf(x1f, 0.0f), 159.0f);
    int iy0 = (int)fminf(fmaxf(y0f, 0.0f), 87.0f);
    int iy1 = (int)fminf(fmaxf(y1f, 0.0f), 87.0f);
    int A = useT ? 64 : 1;
    int Boff = useT ? (cam * NPIX * 64 + lane) : ((cam * 64 + lane) * NPIX);
    float v00 = fsrc[(iy0 * WW + ix0) * A + Boff];
    float v01 = fsrc[(iy1 * WW + ix0) * A + Boff];
    float v10 = fsrc[(iy0 * WW + ix1) * A + Boff];
    float v11 = fsrc[(iy1 * WW + ix1) * A + Boff];
    float fv;                                        // reference corner order
    fv  = (wx0 * wy0 * bx0 * by0) * v00;
    fv += (wx0 * wy1 * bx0 * by1) * v01;
    fv += (wx1 * wy0 * bx1 * by0) * v10;
    fv += (wx1 * wy1 * bx1 * by1) * v11;
    return fv;
}

// 8-output FMA step over 4 channels, weights via wave-uniform scalar loads
#define FMA8_STEP(W0,W1,W2,W3,W4,W5,W6,W7,CG,F0,F1,F2,F3) \
    a0 += W0[CG]*F0; a0 += W0[CG+1]*F1; a0 += W0[CG+2]*F2; a0 += W0[CG+3]*F3; \
    a1 += W1[CG]*F0; a1 += W1[CG+1]*F1; a1 += W1[CG+2]*F2; a1 += W1[CG+3]*F3; \
    a2 += W2[CG]*F0; a2 += W2[CG+1]*F1; a2 += W2[CG+2]*F2; a2 += W2[CG+3]*F3; \
    a3 += W3[CG]*F0; a3 += W3[CG+1]*F1; a3 += W3[CG+2]*F2; a3 += W3[CG+3]*F3; \
    a4 += W4[CG]*F0; a4 += W4[CG+1]*F1; a4 += W4[CG+2]*F2; a4 += W4[CG+3]*F3; \
    a5 += W5[CG]*F0; a5 += W5[CG+1]*F1; a5 += W5[CG+2]*F2; a5 += W5[CG+3]*F3; \
    a6 += W6[CG]*F0; a6 += W6[CG+1]*F1; a6 += W6[CG+2]*F2; a6 += W6[CG+3]*F3; \
    a7 += W7[CG]*F0; a7 += W7[CG+1]*F1; a7 += W7[CG+2]*F2; a7 += W7[CG+3]*F3;

// ---------------- fused kernel: one block = 512 voxels, 8 waves ----------------
__global__ __launch_bounds__(NTH) void vox_fused(
    const float* __restrict__ feats,
    const float* __restrict__ featT,
    const float* __restrict__ mask,
    const float* __restrict__ Kg,
    const float* __restrict__ ext,
    const float* __restrict__ wno,   // [64][65]
    const float* __restrict__ bno,   // [64]
    const float* __restrict__ wo,    // [64][130]
    const float* __restrict__ bo,    // [64]
    float* __restrict__ outp,        // [64][200000]
    int useT)
{
    __shared__ float s_ext[72];
    __shared__ float s_K[54];
    __shared__ float s_F[65 * 66];                 // [channel][entry], stride 66
    __shared__ __align__(16) float4 s_rec1[VB];    // {x,y,z,meta}
    __shared__ __align__(16) float4 s_rec2[2 * VB];
    __shared__ int s_vox[64];
    __shared__ int s_n1, s_n2;

    int tid = threadIdx.x;
    int lane = tid & 63;
    int wv = tid >> 6;               // 0..7
    int base = blockIdx.x * VB;
    int vlim = min(VB, NVOX - base); // last block: 320

    if (tid == 0) { s_n1 = 0; s_n2 = 0; }
    if (tid >= 64 && tid < 136) {
        int i = tid - 64;
        s_ext[i] = ext[(i / 12) * 16 + (i % 12)];
    }
    if (tid >= 192 && tid < 246) {
        int i = tid - 192; int cam = i / 9; int e = i - cam * 9;
        s_K[i] = Kg[cam * 16 + (e / 3) * 4 + (e % 3)];
    }

    // ---- phase 0: zero this block's output window (coalesced float4) ----
    {
        int ng4 = vlim >> 2;                       // float4 groups per row (vlim % 4 == 0)
        for (int i = tid; i < 64 * 128; i += NTH) {
            int r = i >> 7, cg = i & 127;
            if (cg < ng4)
                *(float4*)(outp + (size_t)r * NVOX + base + (cg << 2)) =
                    make_float4(0.f, 0.f, 0.f, 0.f);
        }
    }
    __syncthreads();

    // ---- phase 1: per-voxel geometry over 6 cams (identical FP sequence) ----
    if (tid < vlim) {
        #pragma clang fp contract(off)
        int n = base + tid;
        int xi = n % 100;
        int t = n / 100;
        int yi = t % 100;
        int zi = t / 100;
        float X = -50.0f + (float)xi;
        float Y = -50.0f + (float)yi;
        float Z = -15.0f + 1.5f * (float)zi;
        int cnt = 0, cam0 = 0, cam1 = 0;
        float ax = 0.f, ay = 0.f, az = 0.f, bx = 0.f, by = 0.f, bz = 0.f;
        #pragma unroll
        for (int cam = 0; cam < NC; ++cam) {
            const float* E = s_ext + cam * 12;
            const float* Kk = s_K + cam * 9;
            float vl0 = E[0]*X + E[1]*Y + E[2]*Z + E[3];
            float vl1 = E[4]*X + E[5]*Y + E[6]*Z + E[7];
            float vl2 = E[8]*X + E[9]*Y + E[10]*Z + E[11];
            float c0 = Kk[0]*vl0 + Kk[1]*vl1 + Kk[2]*vl2;
            float c1 = Kk[3]*vl0 + Kk[4]*vl1 + Kk[5]*vl2;
            float c2 = Kk[6]*vl0 + Kk[7]*vl1 + Kk[8]*vl2;
            float pz = c2 + 1e-8f;
            float px = c0 / pz;
            float py = c1 / pz;
            float gx = (px / 159.0f - 0.5f) * 2.0f;
            float gy = (py / 87.0f - 0.5f) * 2.0f;
            float x = ((gx + 1.0f) * 0.5f) * 159.0f;
            float y = ((gy + 1.0f) * 0.5f) * 87.0f;
            float xr = rintf(x), yr = rintf(y);
            bool nv = (xr >= 0.0f) && (xr <= 159.0f) && (yr >= 0.0f) && (yr <= 87.0f);
            float mval = 0.0f;
            if (nv) mval = mask[(cam * HH + (int)yr) * WW + (int)xr];
            bool ok = (mval > 0.5f) && (vl2 > 0.0f) &&
                      !((gx > 1.0f) || (gx < -1.0f) || (gy > 1.0f) || (gy < -1.0f));
            if (ok) {
                if (cnt == 0) { ax = x; ay = y; az = vl2; cam0 = cam; }
                else if (cnt == 1) { bx = x; by = y; bz = vl2; cam1 = cam; }
                ++cnt;
            }
        }
        if (cnt == 1) {
            int s = atomicAdd(&s_n1, 1);
            s_rec1[s] = make_float4(ax, ay, az, __int_as_float((n << 3) | cam0));
        } else if (cnt == 2) {
            int s = atomicAdd(&s_n2, 1);
            s_rec2[2 * s + 0] = make_float4(ax, ay, az, __int_as_float((n << 3) | cam0));
            s_rec2[2 * s + 1] = make_float4(bx, by, bz, __int_as_float((n << 3) | cam1));
        }
    }
    __syncthreads();   // also drains zero-phase stores before any result store

    int n1 = s_n1, n2 = s_n2;
    const float* fsrc = useT ? featT : feats;
    int wvu = __builtin_amdgcn_readfirstlane(wv);
    int obase = wvu * 8;
    const float* w0n = wno + (obase + 0) * 65;
    const float* w1n = wno + (obase + 1) * 65;
    const float* w2n = wno + (obase + 2) * 65;
    const float* w3n = wno + (obase + 3) * 65;
    const float* w4n = wno + (obase + 4) * 65;
    const float* w5n = wno + (obase + 5) * 65;
    const float* w6n = wno + (obase + 6) * 65;
    const float* w7n = wno + (obase + 7) * 65;
    const float* w0o = wo + (obase + 0) * 130;
    const float* w1o = wo + (obase + 1) * 130;
    const float* w2o = wo + (obase + 2) * 130;
    const float* w3o = wo + (obase + 3) * 130;
    const float* w4o = wo + (obase + 4) * 130;
    const float* w5o = wo + (obase + 5) * 130;
    const float* w6o = wo + (obase + 6) * 130;
    const float* w7o = wo + (obase + 7) * 130;

    // ---- count==1 tiles ----
    for (int t0 = 0; t0 < n1; t0 += 64) {
        int tl = min(64, n1 - t0);
        for (int e = wv; e < tl; e += NWV) {
            float4 r = s_rec1[t0 + e];               // wave-uniform LDS broadcast
            int meta = __float_as_int(r.w);
            int cam = meta & 7;
            float fv = gather_bilin(fsrc, useT, lane, cam, r.x, r.y);
            s_F[lane * 66 + e] = fv;
            if (lane == 0) { s_F[64 * 66 + e] = r.z / 100.0f; s_vox[e] = meta >> 3; }
        }
        __syncthreads();
        float a0 = bno[obase + 0], a1 = bno[obase + 1], a2 = bno[obase + 2], a3 = bno[obase + 3];
        float a4 = bno[obase + 4], a5 = bno[obase + 5], a6 = bno[obase + 6], a7 = bno[obase + 7];
        for (int cg = 0; cg < 64; cg += 4) {
            float f0 = s_F[(cg + 0) * 66 + lane];
            float f1 = s_F[(cg + 1) * 66 + lane];
            float f2 = s_F[(cg + 2) * 66 + lane];
            float f3 = s_F[(cg + 3) * 66 + lane];
            FMA8_STEP(w0n, w1n, w2n, w3n, w4n, w5n, w6n, w7n, cg, f0, f1, f2, f3)
        }
        float fd = s_F[64 * 66 + lane];
        a0 += w0n[64] * fd; a1 += w1n[64] * fd; a2 += w2n[64] * fd; a3 += w3n[64] * fd;
        a4 += w4n[64] * fd; a5 += w5n[64] * fd; a6 += w6n[64] * fd; a7 += w7n[64] * fd;
        if (lane < tl) {
            size_t col = (size_t)s_vox[lane];
            outp[(size_t)(obase + 0) * NVOX + col] = elu1(a0);
            outp[(size_t)(obase + 1) * NVOX + col] = elu1(a1);
            outp[(size_t)(obase + 2) * NVOX + col] = elu1(a2);
            outp[(size_t)(obase + 3) * NVOX + col] = elu1(a3);
            outp[(size_t)(obase + 4) * NVOX + col] = elu1(a4);
            outp[(size_t)(obase + 5) * NVOX + col] = elu1(a5);
            outp[(size_t)(obase + 6) * NVOX + col] = elu1(a6);
            outp[(size_t)(obase + 7) * NVOX + col] = elu1(a7);
        }
        __syncthreads();
    }

    // ---- count==2 tiles: two passes over the 65-row F tile ----
    for (int t0 = 0; t0 < n2; t0 += 64) {
        int tl = min(64, n2 - t0);
        for (int e = wv; e < tl; e += NWV) {         // pass A gather: cams {0,3,4}
            float4 r0 = s_rec2[2 * (t0 + e) + 0];
            float4 r1 = s_rec2[2 * (t0 + e) + 1];
            int m0 = __float_as_int(r0.w), m1 = __float_as_int(r1.w);
            int ca = m0 & 7, cb = m1 & 7;
            float fg = 0.0f, dd = 0.0f;
            if (!(ca == 1 || ca == 2 || ca == 5)) {
                fg += gather_bilin(fsrc, useT, lane, ca, r0.x, r0.y);
                dd += r0.z / 100.0f;
            }
            if (!(cb == 1 || cb == 2 || cb == 5)) {
                fg += gather_bilin(fsrc, useT, lane, cb, r1.x, r1.y);
                dd += r1.z / 100.0f;
            }
            s_F[lane * 66 + e] = fg;
            if (lane == 0) { s_F[64 * 66 + e] = dd; s_vox[e] = m0 >> 3; }
        }
        __syncthreads();
        float a0 = bo[obase + 0], a1 = bo[obase + 1], a2 = bo[obase + 2], a3 = bo[obase + 3];
        float a4 = bo[obase + 4], a5 = bo[obase + 5], a6 = bo[obase + 6], a7 = bo[obase + 7];
        for (int cg = 0; cg < 64; cg += 4) {         // pass A compute: cols 0..64
            float f0 = s_F[(cg + 0) * 66 + lane];
            float f1 = s_F[(cg + 1) * 66 + lane];
            float f2 = s_F[(cg + 2) * 66 + lane];
            float f3 = s_F[(cg + 3) * 66 + lane];
            FMA8_STEP(w0o, w1o, w2o, w3o, w4o, w5o, w6o, w7o, cg, f0, f1, f2, f3)
        }
        {
            float fd = s_F[64 * 66 + lane];
            a0 += w0o[64] * fd; a1 += w1o[64] * fd; a2 += w2o[64] * fd; a3 += w3o[64] * fd;
            a4 += w4o[64] * fd; a5 += w5o[64] * fd; a6 += w6o[64] * fd; a7 += w7o[64] * fd;
        }
        __syncthreads();
        for (int e = wv; e < tl; e += NWV) {         // pass B gather: cams {1,2,5}
            float4 r0 = s_rec2[2 * (t0 + e) + 0];
            float4 r1 = s_rec2[2 * (t0 + e) + 1];
            int m0 = __float_as_int(r0.w), m1 = __float_as_int(r1.w);
            int ca = m0 & 7, cb = m1 & 7;
            float fg = 0.0f, dd = 0.0f;
            if (ca == 1 || ca == 2 || ca == 5) {
                fg += gather_bilin(fsrc, useT, lane, ca, r0.x, r0.y);
                dd += r0.z / 100.0f;
            }
            if (cb == 1 || cb == 2 || cb == 5) {
                fg += gather_bilin(fsrc, useT, lane, cb, r1.x, r1.y);
                dd += r1.z / 100.0f;
            }
            s_F[lane * 66 + e] = fg;
            if (lane == 0) s_F[64 * 66 + e] = dd;
        }
        __syncthreads();
        for (int cg = 0; cg < 64; cg += 4) {         // pass B compute: cols 65..129
            float f0 = s_F[(cg + 0) * 66 + lane];
            float f1 = s_F[(cg + 1) * 66 + lane];
            float f2 = s_F[(cg + 2) * 66 + lane];
            float f3 = s_F[(cg + 3) * 66 + lane];
            int cgo = cg + 65;
            FMA8_STEP(w0o, w1o, w2o, w3o, w4o, w5o, w6o, w7o, cgo, f0, f1, f2, f3)
        }
        {
            float fd = s_F[64 * 66 + lane];
            a0 += w0o[129] * fd; a1 += w1o[129] * fd; a2 += w2o[129] * fd; a3 += w3o[129] * fd;
            a4 += w4o[129] * fd; a5 += w5o[129] * fd; a6 += w6o[129] * fd; a7 += w7o[129] * fd;
        }
        if (lane < tl) {
            size_t col = (size_t)s_vox[lane];
            outp[(size_t)(obase + 0) * NVOX + col] = elu1(a0);
            outp[(size_t)(obase + 1) * NVOX + col] = elu1(a1);
            outp[(size_t)(obase + 2) * NVOX + col] = elu1(a2);
            outp[(size_t)(obase + 3) * NVOX + col] = elu1(a3);
            outp[(size_t)(obase + 4) * NVOX + col] = elu1(a4);
            outp[(size_t)(obase + 5) * NVOX + col] = elu1(a5);
            outp[(size_t)(obase + 6) * NVOX + col] = elu1(a6);
            outp[(size_t)(obase + 7) * NVOX + col] = elu1(a7);
        }
        __syncthreads();
    }
}

extern "C" void kernel_launch(void* const* d_in, const int* in_sizes, int n_in,
                              void* d_out, int out_size, void* d_ws, size_t ws_size,
                              hipStream_t stream) {
    const float* feats = (const float*)d_in[0];
    const float* mask  = (const float*)d_in[1];
    const float* Kg    = (const float*)d_in[2];
    const float* ext   = (const float*)d_in[3];
    const float* wno   = (const float*)d_in[4];
    const float* bno   = (const float*)d_in[5];
    const float* wo    = (const float*)d_in[6];
    const float* bo    = (const float*)d_in[7];
    float* outp = (float*)d_out;
    float* featT = (float*)d_ws;

    int useT = (ws_size >= (size_t)FEATT_BYTES) ? 1 : 0;
    if (useT) {
        transpose_feats<<<NC * 220, 256, 0, stream>>>(feats, featT);
    }
    int nblk = (NVOX + VB - 1) / VB;                 // 391
    vox_fused<<<nblk, NTH, 0, stream>>>(feats, featT, mask, Kg, ext,
                                        wno, bno, wo, bo, outp, useT);
}

// Round 9
// 167.303 us; speedup vs baseline: 1.1228x; 1.0627x over previous
//
#include <hip/hip_runtime.h>
#include <cmath>

#define NC 6
#define CF 64
#define HH 88
#define WW 160
#define NPIX 14080     // 88*160
#define NVOX 200000
#define VPRE 64
#define VB 128         // voxels per block (thread = voxel)
#define NTH 256        // 4 waves
#define NWV 4

typedef unsigned int u32;

#define FEATT_BYTES  (6u * 64u * 14080u * 4u)            // 21,626,880

// ---------------- transpose [6][64][H*W] -> [6][H*W][64] (f32) ----------------
__global__ __launch_bounds__(256) void transpose_feats(const float* __restrict__ in,
                                                       float* __restrict__ out) {
    __shared__ float tile[64 * 65];
    int blk = blockIdx.x;            // 6 * 220
    int c = blk / 220;
    int p0 = (blk - c * 220) * 64;
    int tid = threadIdx.x;
    int lane = tid & 63;
    int quad = tid >> 6;
    for (int r = quad; r < 64; r += 4)
        tile[r * 65 + lane] = in[(c * 64 + r) * NPIX + p0 + lane];
    __syncthreads();
    for (int r = quad; r < 64; r += 4)
        out[((c * NPIX) + p0 + r) * 64 + lane] = tile[lane * 65 + r];
}

__device__ __forceinline__ float elu1(float x) { return x > 0.0f ? x : expm1f(x); }

// bilinear gather: voxel uniform across wave, lane = channel. Math identical to r3..r8.
__device__ __forceinline__ float gather_bilin(const float* __restrict__ fsrc, int useT,
                                              int lane, int cam, float x, float y) {
    float x0f = floorf(x), y0f = floorf(y);
    float wx1 = x - x0f, wx0 = 1.0f - wx1;
    float wy1 = y - y0f, wy0 = 1.0f - wy1;
    float x1f = x0f + 1.0f, y1f = y0f + 1.0f;
    float bx0 = (x0f >= 0.0f && x0f <= 159.0f) ? 1.0f : 0.0f;
    float bx1 = (x1f >= 0.0f && x1f <= 159.0f) ? 1.0f : 0.0f;
    float by0 = (y0f >= 0.0f && y0f <= 87.0f) ? 1.0f : 0.0f;
    float by1 = (y1f >= 0.0f && y1f <= 87.0f) ? 1.0f : 0.0f;
    int ix0 = (int)fminf(fmaxf(x0f, 0.0f), 159.0f);
    int ix1 = (int)fminf(fmaxf(x1f, 0.0f), 159.0f);
    int iy0 = (int)fminf(fmaxf(y0f, 0.0f), 87.0f);
    int iy1 = (int)fminf(fmaxf(y1f, 0.0f), 87.0f);
    int A = useT ? 64 : 1;
    int Boff = useT ? (cam * NPIX * 64 + lane) : ((cam * 64 + lane) * NPIX);
    float v00 = fsrc[(iy0 * WW + ix0) * A + Boff];
    float v01 = fsrc[(iy1 * WW + ix0) * A + Boff];
    float v10 = fsrc[(iy0 * WW + ix1) * A + Boff];
    float v11 = fsrc[(iy1 * WW + ix1) * A + Boff];
    float fv;                                        // reference corner order
    fv  = (wx0 * wy0 * bx0 * by0) * v00;
    fv += (wx0 * wy1 * bx0 * by1) * v01;
    fv += (wx1 * wy0 * bx1 * by0) * v10;
    fv += (wx1 * wy1 * bx1 * by1) * v11;
    return fv;
}

// 16-output FMA step over 4 channels; weights via wave-uniform scalar loads.
// WB = weight row base pointer, RS = row stride (65 or 130), CG = column base.
#define FMA16_STEP(WB,RS,CG,F0,F1,F2,F3) \
    a0  += WB[ 0*RS+CG]*F0; a0  += WB[ 0*RS+CG+1]*F1; a0  += WB[ 0*RS+CG+2]*F2; a0  += WB[ 0*RS+CG+3]*F3; \
    a1  += WB[ 1*RS+CG]*F0; a1  += WB[ 1*RS+CG+1]*F1; a1  += WB[ 1*RS+CG+2]*F2; a1  += WB[ 1*RS+CG+3]*F3; \
    a2  += WB[ 2*RS+CG]*F0; a2  += WB[ 2*RS+CG+1]*F1; a2  += WB[ 2*RS+CG+2]*F2; a2  += WB[ 2*RS+CG+3]*F3; \
    a3  += WB[ 3*RS+CG]*F0; a3  += WB[ 3*RS+CG+1]*F1; a3  += WB[ 3*RS+CG+2]*F2; a3  += WB[ 3*RS+CG+3]*F3; \
    a4  += WB[ 4*RS+CG]*F0; a4  += WB[ 4*RS+CG+1]*F1; a4  += WB[ 4*RS+CG+2]*F2; a4  += WB[ 4*RS+CG+3]*F3; \
    a5  += WB[ 5*RS+CG]*F0; a5  += WB[ 5*RS+CG+1]*F1; a5  += WB[ 5*RS+CG+2]*F2; a5  += WB[ 5*RS+CG+3]*F3; \
    a6  += WB[ 6*RS+CG]*F0; a6  += WB[ 6*RS+CG+1]*F1; a6  += WB[ 6*RS+CG+2]*F2; a6  += WB[ 6*RS+CG+3]*F3; \
    a7  += WB[ 7*RS+CG]*F0; a7  += WB[ 7*RS+CG+1]*F1; a7  += WB[ 7*RS+CG+2]*F2; a7  += WB[ 7*RS+CG+3]*F3; \
    a8  += WB[ 8*RS+CG]*F0; a8  += WB[ 8*RS+CG+1]*F1; a8  += WB[ 8*RS+CG+2]*F2; a8  += WB[ 8*RS+CG+3]*F3; \
    a9  += WB[ 9*RS+CG]*F0; a9  += WB[ 9*RS+CG+1]*F1; a9  += WB[ 9*RS+CG+2]*F2; a9  += WB[ 9*RS+CG+3]*F3; \
    a10 += WB[10*RS+CG]*F0; a10 += WB[10*RS+CG+1]*F1; a10 += WB[10*RS+CG+2]*F2; a10 += WB[10*RS+CG+3]*F3; \
    a11 += WB[11*RS+CG]*F0; a11 += WB[11*RS+CG+1]*F1; a11 += WB[11*RS+CG+2]*F2; a11 += WB[11*RS+CG+3]*F3; \
    a12 += WB[12*RS+CG]*F0; a12 += WB[12*RS+CG+1]*F1; a12 += WB[12*RS+CG+2]*F2; a12 += WB[12*RS+CG+3]*F3; \
    a13 += WB[13*RS+CG]*F0; a13 += WB[13*RS+CG+1]*F1; a13 += WB[13*RS+CG+2]*F2; a13 += WB[13*RS+CG+3]*F3; \
    a14 += WB[14*RS+CG]*F0; a14 += WB[14*RS+CG+1]*F1; a14 += WB[14*RS+CG+2]*F2; a14 += WB[14*RS+CG+3]*F3; \
    a15 += WB[15*RS+CG]*F0; a15 += WB[15*RS+CG+1]*F1; a15 += WB[15*RS+CG+2]*F2; a15 += WB[15*RS+CG+3]*F3;

#define FMA16_DEPTH(WB,RS,CI,FD) \
    a0  += WB[ 0*RS+CI]*FD; a1  += WB[ 1*RS+CI]*FD; a2  += WB[ 2*RS+CI]*FD; a3  += WB[ 3*RS+CI]*FD; \
    a4  += WB[ 4*RS+CI]*FD; a5  += WB[ 5*RS+CI]*FD; a6  += WB[ 6*RS+CI]*FD; a7  += WB[ 7*RS+CI]*FD; \
    a8  += WB[ 8*RS+CI]*FD; a9  += WB[ 9*RS+CI]*FD; a10 += WB[10*RS+CI]*FD; a11 += WB[11*RS+CI]*FD; \
    a12 += WB[12*RS+CI]*FD; a13 += WB[13*RS+CI]*FD; a14 += WB[14*RS+CI]*FD; a15 += WB[15*RS+CI]*FD;

#define STORE16(COL) \
    outp[(size_t)(obase + 0)  * NVOX + COL] = elu1(a0);  \
    outp[(size_t)(obase + 1)  * NVOX + COL] = elu1(a1);  \
    outp[(size_t)(obase + 2)  * NVOX + COL] = elu1(a2);  \
    outp[(size_t)(obase + 3)  * NVOX + COL] = elu1(a3);  \
    outp[(size_t)(obase + 4)  * NVOX + COL] = elu1(a4);  \
    outp[(size_t)(obase + 5)  * NVOX + COL] = elu1(a5);  \
    outp[(size_t)(obase + 6)  * NVOX + COL] = elu1(a6);  \
    outp[(size_t)(obase + 7)  * NVOX + COL] = elu1(a7);  \
    outp[(size_t)(obase + 8)  * NVOX + COL] = elu1(a8);  \
    outp[(size_t)(obase + 9)  * NVOX + COL] = elu1(a9);  \
    outp[(size_t)(obase + 10) * NVOX + COL] = elu1(a10); \
    outp[(size_t)(obase + 11) * NVOX + COL] = elu1(a11); \
    outp[(size_t)(obase + 12) * NVOX + COL] = elu1(a12); \
    outp[(size_t)(obase + 13) * NVOX + COL] = elu1(a13); \
    outp[(size_t)(obase + 14) * NVOX + COL] = elu1(a14); \
    outp[(size_t)(obase + 15) * NVOX + COL] = elu1(a15);

// ---------------- fused kernel: one block = 128 voxels, 4 waves ----------------
__global__ __launch_bounds__(NTH) void vox_fused(
    const float* __restrict__ feats,
    const float* __restrict__ featT,
    const float* __restrict__ mask,
    const float* __restrict__ Kg,
    const float* __restrict__ ext,
    const float* __restrict__ wno,   // [64][65]
    const float* __restrict__ bno,   // [64]
    const float* __restrict__ wo,    // [64][130]
    const float* __restrict__ bo,    // [64]
    float* __restrict__ outp,        // [64][200000]
    int useT)
{
    __shared__ float s_ext[72];
    __shared__ float s_K[54];
    __shared__ float s_F[65 * 66];                 // [channel][entry], stride 66
    __shared__ __align__(16) float4 s_rec1[VB];    // {x,y,z,meta}
    __shared__ __align__(16) float4 s_rec2[2 * VB];
    __shared__ int s_vox[64];
    __shared__ int s_n1, s_n2;

    int tid = threadIdx.x;
    int lane = tid & 63;
    int wv = tid >> 6;               // 0..3
    int base = blockIdx.x * VB;
    int vlim = min(VB, NVOX - base); // last block: 64

    if (tid == 0) { s_n1 = 0; s_n2 = 0; }
    if (tid >= 64 && tid < 136) {
        int i = tid - 64;
        s_ext[i] = ext[(i / 12) * 16 + (i % 12)];
    }
    if (tid >= 192 && tid < 246) {
        int i = tid - 192; int cam = i / 9; int e = i - cam * 9;
        s_K[i] = Kg[cam * 16 + (e / 3) * 4 + (e % 3)];
    }

    // ---- phase 0: zero this block's output window (coalesced float4) ----
    {
        int ng4 = vlim >> 2;                       // float4 groups per row (vlim % 4 == 0)
        for (int i = tid; i < 64 * (VB / 4); i += NTH) {
            int r = i >> 5, cg = i & ((VB / 4) - 1);
            if (cg < ng4)
                *(float4*)(outp + (size_t)r * NVOX + base + (cg << 2)) =
                    make_float4(0.f, 0.f, 0.f, 0.f);
        }
    }
    __syncthreads();

    // ---- phase 1: per-voxel geometry over 6 cams (identical FP sequence) ----
    if (tid < vlim) {
        #pragma clang fp contract(off)
        int n = base + tid;
        int xi = n % 100;
        int t = n / 100;
        int yi = t % 100;
        int zi = t / 100;
        float X = -50.0f + (float)xi;
        float Y = -50.0f + (float)yi;
        float Z = -15.0f + 1.5f * (float)zi;
        int cnt = 0, cam0 = 0, cam1 = 0;
        float ax = 0.f, ay = 0.f, az = 0.f, bx = 0.f, by = 0.f, bz = 0.f;
        #pragma unroll
        for (int cam = 0; cam < NC; ++cam) {
            const float* E = s_ext + cam * 12;
            const float* Kk = s_K + cam * 9;
            float vl0 = E[0]*X + E[1]*Y + E[2]*Z + E[3];
            float vl1 = E[4]*X + E[5]*Y + E[6]*Z + E[7];
            float vl2 = E[8]*X + E[9]*Y + E[10]*Z + E[11];
            float c0 = Kk[0]*vl0 + Kk[1]*vl1 + Kk[2]*vl2;
            float c1 = Kk[3]*vl0 + Kk[4]*vl1 + Kk[5]*vl2;
            float c2 = Kk[6]*vl0 + Kk[7]*vl1 + Kk[8]*vl2;
            float pz = c2 + 1e-8f;
            float px = c0 / pz;
            float py = c1 / pz;
            float gx = (px / 159.0f - 0.5f) * 2.0f;
            float gy = (py / 87.0f - 0.5f) * 2.0f;
            float x = ((gx + 1.0f) * 0.5f) * 159.0f;
            float y = ((gy + 1.0f) * 0.5f) * 87.0f;
            float xr = rintf(x), yr = rintf(y);
            bool nv = (xr >= 0.0f) && (xr <= 159.0f) && (yr >= 0.0f) && (yr <= 87.0f);
            float mval = 0.0f;
            if (nv) mval = mask[(cam * HH + (int)yr) * WW + (int)xr];
            bool ok = (mval > 0.5f) && (vl2 > 0.0f) &&
                      !((gx > 1.0f) || (gx < -1.0f) || (gy > 1.0f) || (gy < -1.0f));
            if (ok) {
                if (cnt == 0) { ax = x; ay = y; az = vl2; cam0 = cam; }
                else if (cnt == 1) { bx = x; by = y; bz = vl2; cam1 = cam; }
                ++cnt;
            }
        }
        if (cnt == 1) {
            int s = atomicAdd(&s_n1, 1);
            s_rec1[s] = make_float4(ax, ay, az, __int_as_float((n << 3) | cam0));
        } else if (cnt == 2) {
            int s = atomicAdd(&s_n2, 1);
            s_rec2[2 * s + 0] = make_float4(ax, ay, az, __int_as_float((n << 3) | cam0));
            s_rec2[2 * s + 1] = make_float4(bx, by, bz, __int_as_float((n << 3) | cam1));
        }
    }
    __syncthreads();   // also orders zero-phase stores before result stores

    int n1 = s_n1, n2 = s_n2;
    const float* fsrc = useT ? featT : feats;
    int wvu = __builtin_amdgcn_readfirstlane(wv);
    int obase = wvu * 16;
    const float* wbn = wno + obase * 65;   // 16 rows, stride 65
    const float* wbo = wo + obase * 130;   // 16 rows, stride 130

    // ---- count==1 tiles ----
    for (int t0 = 0; t0 < n1; t0 += 64) {
        int tl = min(64, n1 - t0);
        for (int e = wv; e < tl; e += NWV) {
            float4 r = s_rec1[t0 + e];               // wave-uniform LDS broadcast
            int meta = __float_as_int(r.w);
            int cam = meta & 7;
            float fv = gather_bilin(fsrc, useT, lane, cam, r.x, r.y);
            s_F[lane * 66 + e] = fv;
            if (lane == 0) { s_F[64 * 66 + e] = r.z / 100.0f; s_vox[e] = meta >> 3; }
        }
        __syncthreads();
        float a0  = bno[obase + 0],  a1  = bno[obase + 1],  a2  = bno[obase + 2],  a3  = bno[obase + 3];
        float a4  = bno[obase + 4],  a5  = bno[obase + 5],  a6  = bno[obase + 6],  a7  = bno[obase + 7];
        float a8  = bno[obase + 8],  a9  = bno[obase + 9],  a10 = bno[obase + 10], a11 = bno[obase + 11];
        float a12 = bno[obase + 12], a13 = bno[obase + 13], a14 = bno[obase + 14], a15 = bno[obase + 15];
        for (int cg = 0; cg < 64; cg += 4) {
            float f0 = s_F[(cg + 0) * 66 + lane];
            float f1 = s_F[(cg + 1) * 66 + lane];
            float f2 = s_F[(cg + 2) * 66 + lane];
            float f3 = s_F[(cg + 3) * 66 + lane];
            FMA16_STEP(wbn, 65, cg, f0, f1, f2, f3)
        }
        {
            float fd = s_F[64 * 66 + lane];
            FMA16_DEPTH(wbn, 65, 64, fd)
        }
        if (lane < tl) {
            size_t col = (size_t)s_vox[lane];
            STORE16(col)
        }
        __syncthreads();
    }

    // ---- count==2 tiles: two passes over the 65-row F tile ----
    for (int t0 = 0; t0 < n2; t0 += 64) {
        int tl = min(64, n2 - t0);
        for (int e = wv; e < tl; e += NWV) {         // pass A gather: cams {0,3,4}
            float4 r0 = s_rec2[2 * (t0 + e) + 0];
            float4 r1 = s_rec2[2 * (t0 + e) + 1];
            int m0 = __float_as_int(r0.w), m1 = __float_as_int(r1.w);
            int ca = m0 & 7, cb = m1 & 7;
            float fg = 0.0f, dd = 0.0f;
            if (!(ca == 1 || ca == 2 || ca == 5)) {
                fg += gather_bilin(fsrc, useT, lane, ca, r0.x, r0.y);
                dd += r0.z / 100.0f;
            }
            if (!(cb == 1 || cb == 2 || cb == 5)) {
                fg += gather_bilin(fsrc, useT, lane, cb, r1.x, r1.y);
                dd += r1.z / 100.0f;
            }
            s_F[lane * 66 + e] = fg;
            if (lane == 0) { s_F[64 * 66 + e] = dd; s_vox[e] = m0 >> 3; }
        }
        __syncthreads();
        float a0  = bo[obase + 0],  a1  = bo[obase + 1],  a2  = bo[obase + 2],  a3  = bo[obase + 3];
        float a4  = bo[obase + 4],  a5  = bo[obase + 5],  a6  = bo[obase + 6],  a7  = bo[obase + 7];
        float a8  = bo[obase + 8],  a9  = bo[obase + 9],  a10 = bo[obase + 10], a11 = bo[obase + 11];
        float a12 = bo[obase + 12], a13 = bo[obase + 13], a14 = bo[obase + 14], a15 = bo[obase + 15];
        for (int cg = 0; cg < 64; cg += 4) {         // pass A compute: cols 0..64
            float f0 = s_F[(cg + 0) * 66 + lane];
            float f1 = s_F[(cg + 1) * 66 + lane];
            float f2 = s_F[(cg + 2) * 66 + lane];
            float f3 = s_F[(cg + 3) * 66 + lane];
            FMA16_STEP(wbo, 130, cg, f0, f1, f2, f3)
        }
        {
            float fd = s_F[64 * 66 + lane];
            FMA16_DEPTH(wbo, 130, 64, fd)
        }
        __syncthreads();
        for (int e = wv; e < tl; e += NWV) {         // pass B gather: cams {1,2,5}
            float4 r0 = s_rec2[2 * (t0 + e) + 0];
            float4 r1 = s_rec2[2 * (t0 + e) + 1];
            int m0 = __float_as_int(r0.w), m1 = __float_as_int(r1.w);
            int ca = m0 & 7, cb = m1 & 7;
            float fg = 0.0f, dd = 0.0f;
            if (ca == 1 || ca == 2 || ca == 5) {
                fg += gather_bilin(fsrc, useT, lane, ca, r0.x, r0.y);
                dd += r0.z / 100.0f;
            }
            if (cb == 1 || cb == 2 || cb == 5) {
                fg += gather_bilin(fsrc, useT, lane, cb, r1.x, r1.y);
                dd += r1.z / 100.0f;
            }
            s_F[lane * 66 + e] = fg;
            if (lane == 0) s_F[64 * 66 + e] = dd;
        }
        __syncthreads();
        for (int cg = 0; cg < 64; cg += 4) {         // pass B compute: cols 65..129
            float f0 = s_F[(cg + 0) * 66 + lane];
            float f1 = s_F[(cg + 1) * 66 + lane];
            float f2 = s_F[(cg + 2) * 66 + lane];
            float f3 = s_F[(cg + 3) * 66 + lane];
            int cgo = cg + 65;
            FMA16_STEP(wbo, 130, cgo, f0, f1, f2, f3)
        }
        {
            float fd = s_F[64 * 66 + lane];
            FMA16_DEPTH(wbo, 130, 129, fd)
        }
        if (lane < tl) {
            size_t col = (size_t)s_vox[lane];
            STORE16(col)
        }
        __syncthreads();
    }
}

extern "C" void kernel_launch(void* const* d_in, const int* in_sizes, int n_in,
                              void* d_out, int out_size, void* d_ws, size_t ws_size,
                              hipStream_t stream) {
    const float* feats = (const float*)d_in[0];
    const float* mask  = (const float*)d_in[1];
    const float* Kg    = (const float*)d_in[2];
    const float* ext   = (const float*)d_in[3];
    const float* wno   = (const float*)d_in[4];
    const float* bno   = (const float*)d_in[5];
    const float* wo    = (const float*)d_in[6];
    const float* bo    = (const float*)d_in[7];
    float* outp = (float*)d_out;
    float* featT = (float*)d_ws;

    int useT = (ws_size >= (size_t)FEATT_BYTES) ? 1 : 0;
    if (useT) {
        transpose_feats<<<NC * 220, 256, 0, stream>>>(feats, featT);
    }
    int nblk = (NVOX + VB - 1) / VB;                 // 1563
    vox_fused<<<nblk, NTH, 0, stream>>>(feats, featT, mask, Kg, ext,
                                        wno, bno, wo, bo, outp, useT);
}

// Round 10
// 162.525 us; speedup vs baseline: 1.1558x; 1.0294x over previous
//
#include <hip/hip_runtime.h>
#include <cmath>

#define NC 6
#define CF 64
#define HH 88
#define WW 160
#define NPIX 14080     // 88*160
#define NVOX 200000
#define VPRE 64
#define VB 128         // voxels per block (thread = voxel for geometry)
#define NTH 512        // 8 waves
#define NWV 8

typedef unsigned int u32;

#define FEATT_BYTES  (6u * 64u * 14080u * 4u)            // 21,626,880

// ---------------- transpose [6][64][H*W] -> [6][H*W][64] (f32) ----------------
__global__ __launch_bounds__(256) void transpose_feats(const float* __restrict__ in,
                                                       float* __restrict__ out) {
    __shared__ float tile[64 * 65];
    int blk = blockIdx.x;            // 6 * 220
    int c = blk / 220;
    int p0 = (blk - c * 220) * 64;
    int tid = threadIdx.x;
    int lane = tid & 63;
    int quad = tid >> 6;
    for (int r = quad; r < 64; r += 4)
        tile[r * 65 + lane] = in[(c * 64 + r) * NPIX + p0 + lane];
    __syncthreads();
    for (int r = quad; r < 64; r += 4)
        out[((c * NPIX) + p0 + r) * 64 + lane] = tile[lane * 65 + r];
}

__device__ __forceinline__ float elu1(float x) { return x > 0.0f ? x : expm1f(x); }

// bilinear gather: voxel uniform across wave, lane = channel. Math identical to r3..r9.
__device__ __forceinline__ float gather_bilin(const float* __restrict__ fsrc, int useT,
                                              int lane, int cam, float x, float y) {
    float x0f = floorf(x), y0f = floorf(y);
    float wx1 = x - x0f, wx0 = 1.0f - wx1;
    float wy1 = y - y0f, wy0 = 1.0f - wy1;
    float x1f = x0f + 1.0f, y1f = y0f + 1.0f;
    float bx0 = (x0f >= 0.0f && x0f <= 159.0f) ? 1.0f : 0.0f;
    float bx1 = (x1f >= 0.0f && x1f <= 159.0f) ? 1.0f : 0.0f;
    float by0 = (y0f >= 0.0f && y0f <= 87.0f) ? 1.0f : 0.0f;
    float by1 = (y1f >= 0.0f && y1f <= 87.0f) ? 1.0f : 0.0f;
    int ix0 = (int)fminf(fmaxf(x0f, 0.0f), 159.0f);
    int ix1 = (int)fminf(fmaxf(x1f, 0.0f), 159.0f);
    int iy0 = (int)fminf(fmaxf(y0f, 0.0f), 87.0f);
    int iy1 = (int)fminf(fmaxf(y1f, 0.0f), 87.0f);
    int A = useT ? 64 : 1;
    int Boff = useT ? (cam * NPIX * 64 + lane) : ((cam * 64 + lane) * NPIX);
    float v00 = fsrc[(iy0 * WW + ix0) * A + Boff];
    float v01 = fsrc[(iy1 * WW + ix0) * A + Boff];
    float v10 = fsrc[(iy0 * WW + ix1) * A + Boff];
    float v11 = fsrc[(iy1 * WW + ix1) * A + Boff];
    float fv;                                        // reference corner order
    fv  = (wx0 * wy0 * bx0 * by0) * v00;
    fv += (wx0 * wy1 * bx0 * by1) * v01;
    fv += (wx1 * wy0 * bx1 * by0) * v10;
    fv += (wx1 * wy1 * bx1 * by1) * v11;
    return fv;
}

// 8-output FMA step over 4 channels, weights via wave-uniform scalar loads
#define FMA8_STEP(W0,W1,W2,W3,W4,W5,W6,W7,CG,F0,F1,F2,F3) \
    a0 += W0[CG]*F0; a0 += W0[CG+1]*F1; a0 += W0[CG+2]*F2; a0 += W0[CG+3]*F3; \
    a1 += W1[CG]*F0; a1 += W1[CG+1]*F1; a1 += W1[CG+2]*F2; a1 += W1[CG+3]*F3; \
    a2 += W2[CG]*F0; a2 += W2[CG+1]*F1; a2 += W2[CG+2]*F2; a2 += W2[CG+3]*F3; \
    a3 += W3[CG]*F0; a3 += W3[CG+1]*F1; a3 += W3[CG+2]*F2; a3 += W3[CG+3]*F3; \
    a4 += W4[CG]*F0; a4 += W4[CG+1]*F1; a4 += W4[CG+2]*F2; a4 += W4[CG+3]*F3; \
    a5 += W5[CG]*F0; a5 += W5[CG+1]*F1; a5 += W5[CG+2]*F2; a5 += W5[CG+3]*F3; \
    a6 += W6[CG]*F0; a6 += W6[CG+1]*F1; a6 += W6[CG+2]*F2; a6 += W6[CG+3]*F3; \
    a7 += W7[CG]*F0; a7 += W7[CG+1]*F1; a7 += W7[CG+2]*F2; a7 += W7[CG+3]*F3;

#define STORE8(COL) \
    outp[(size_t)(obase + 0) * NVOX + COL] = elu1(a0); \
    outp[(size_t)(obase + 1) * NVOX + COL] = elu1(a1); \
    outp[(size_t)(obase + 2) * NVOX + COL] = elu1(a2); \
    outp[(size_t)(obase + 3) * NVOX + COL] = elu1(a3); \
    outp[(size_t)(obase + 4) * NVOX + COL] = elu1(a4); \
    outp[(size_t)(obase + 5) * NVOX + COL] = elu1(a5); \
    outp[(size_t)(obase + 6) * NVOX + COL] = elu1(a6); \
    outp[(size_t)(obase + 7) * NVOX + COL] = elu1(a7);

// ---------------- fused kernel: one block = 128 voxels, 8 waves ----------------
__global__ __launch_bounds__(NTH) void vox_fused(
    const float* __restrict__ feats,
    const float* __restrict__ featT,
    const float* __restrict__ mask,
    const float* __restrict__ Kg,
    const float* __restrict__ ext,
    const float* __restrict__ wno,   // [64][65]
    const float* __restrict__ bno,   // [64]
    const float* __restrict__ wo,    // [64][130]
    const float* __restrict__ bo,    // [64]
    float* __restrict__ outp,        // [64][200000]
    int useT)
{
    __shared__ float s_ext[72];
    __shared__ float s_K[54];
    __shared__ float s_F[65 * 66];                 // [channel][entry], stride 66
    __shared__ __align__(16) float4 s_rec1[VB];    // {x,y,z,meta}
    __shared__ __align__(16) float4 s_rec2[2 * VB];
    __shared__ int s_vox[64];
    __shared__ int s_n1, s_n2;

    int tid = threadIdx.x;
    int lane = tid & 63;
    int wv = tid >> 6;               // 0..7
    int base = blockIdx.x * VB;
    int vlim = min(VB, NVOX - base); // last block: 64

    if (tid == 0) { s_n1 = 0; s_n2 = 0; }
    if (tid >= 64 && tid < 136) {
        int i = tid - 64;
        s_ext[i] = ext[(i / 12) * 16 + (i % 12)];
    }
    if (tid >= 192 && tid < 246) {
        int i = tid - 192; int cam = i / 9; int e = i - cam * 9;
        s_K[i] = Kg[cam * 16 + (e / 3) * 4 + (e % 3)];
    }

    // ---- phase 0: zero this block's output window (coalesced float4) ----
    {
        int ng4 = vlim >> 2;                       // float4 groups per row
        for (int i = tid; i < 64 * (VB / 4); i += NTH) {
            int r = i >> 5, cg = i & ((VB / 4) - 1);
            if (cg < ng4)
                *(float4*)(outp + (size_t)r * NVOX + base + (cg << 2)) =
                    make_float4(0.f, 0.f, 0.f, 0.f);
        }
    }
    __syncthreads();

    // ---- phase 1: per-voxel geometry over 6 cams (identical FP sequence) ----
    if (tid < vlim) {
        #pragma clang fp contract(off)
        int n = base + tid;
        int xi = n % 100;
        int t = n / 100;
        int yi = t % 100;
        int zi = t / 100;
        float X = -50.0f + (float)xi;
        float Y = -50.0f + (float)yi;
        float Z = -15.0f + 1.5f * (float)zi;
        int cnt = 0, cam0 = 0, cam1 = 0;
        float ax = 0.f, ay = 0.f, az = 0.f, bx = 0.f, by = 0.f, bz = 0.f;
        #pragma unroll
        for (int cam = 0; cam < NC; ++cam) {
            const float* E = s_ext + cam * 12;
            const float* Kk = s_K + cam * 9;
            float vl0 = E[0]*X + E[1]*Y + E[2]*Z + E[3];
            float vl1 = E[4]*X + E[5]*Y + E[6]*Z + E[7];
            float vl2 = E[8]*X + E[9]*Y + E[10]*Z + E[11];
            float c0 = Kk[0]*vl0 + Kk[1]*vl1 + Kk[2]*vl2;
            float c1 = Kk[3]*vl0 + Kk[4]*vl1 + Kk[5]*vl2;
            float c2 = Kk[6]*vl0 + Kk[7]*vl1 + Kk[8]*vl2;
            float pz = c2 + 1e-8f;
            float px = c0 / pz;
            float py = c1 / pz;
            float gx = (px / 159.0f - 0.5f) * 2.0f;
            float gy = (py / 87.0f - 0.5f) * 2.0f;
            float x = ((gx + 1.0f) * 0.5f) * 159.0f;
            float y = ((gy + 1.0f) * 0.5f) * 87.0f;
            float xr = rintf(x), yr = rintf(y);
            bool nv = (xr >= 0.0f) && (xr <= 159.0f) && (yr >= 0.0f) && (yr <= 87.0f);
            float mval = 0.0f;
            if (nv) mval = mask[(cam * HH + (int)yr) * WW + (int)xr];
            bool ok = (mval > 0.5f) && (vl2 > 0.0f) &&
                      !((gx > 1.0f) || (gx < -1.0f) || (gy > 1.0f) || (gy < -1.0f));
            if (ok) {
                if (cnt == 0) { ax = x; ay = y; az = vl2; cam0 = cam; }
                else if (cnt == 1) { bx = x; by = y; bz = vl2; cam1 = cam; }
                ++cnt;
            }
        }
        if (cnt == 1) {
            int s = atomicAdd(&s_n1, 1);
            s_rec1[s] = make_float4(ax, ay, az, __int_as_float((n << 3) | cam0));
        } else if (cnt == 2) {
            int s = atomicAdd(&s_n2, 1);
            s_rec2[2 * s + 0] = make_float4(ax, ay, az, __int_as_float((n << 3) | cam0));
            s_rec2[2 * s + 1] = make_float4(bx, by, bz, __int_as_float((n << 3) | cam1));
        }
    }
    __syncthreads();   // also orders zero-phase stores before result stores

    int n1 = s_n1, n2 = s_n2;
    const float* fsrc = useT ? featT : feats;
    int wvu = __builtin_amdgcn_readfirstlane(wv);
    int obase = wvu * 8;
    const float* w0n = wno + (obase + 0) * 65;
    const float* w1n = wno + (obase + 1) * 65;
    const float* w2n = wno + (obase + 2) * 65;
    const float* w3n = wno + (obase + 3) * 65;
    const float* w4n = wno + (obase + 4) * 65;
    const float* w5n = wno + (obase + 5) * 65;
    const float* w6n = wno + (obase + 6) * 65;
    const float* w7n = wno + (obase + 7) * 65;
    const float* w0o = wo + (obase + 0) * 130;
    const float* w1o = wo + (obase + 1) * 130;
    const float* w2o = wo + (obase + 2) * 130;
    const float* w3o = wo + (obase + 3) * 130;
    const float* w4o = wo + (obase + 4) * 130;
    const float* w5o = wo + (obase + 5) * 130;
    const float* w6o = wo + (obase + 6) * 130;
    const float* w7o = wo + (obase + 7) * 130;

    // ---- count==1 tiles ----
    for (int t0 = 0; t0 < n1; t0 += 64) {
        int tl = min(64, n1 - t0);
        for (int e = wv; e < tl; e += NWV) {
            float4 r = s_rec1[t0 + e];               // wave-uniform LDS broadcast
            int meta = __float_as_int(r.w);
            int cam = meta & 7;
            float fv = gather_bilin(fsrc, useT, lane, cam, r.x, r.y);
            s_F[lane * 66 + e] = fv;
            if (lane == 0) { s_F[64 * 66 + e] = r.z / 100.0f; s_vox[e] = meta >> 3; }
        }
        __syncthreads();
        float a0 = bno[obase + 0], a1 = bno[obase + 1], a2 = bno[obase + 2], a3 = bno[obase + 3];
        float a4 = bno[obase + 4], a5 = bno[obase + 5], a6 = bno[obase + 6], a7 = bno[obase + 7];
        for (int cg = 0; cg < 64; cg += 4) {
            float f0 = s_F[(cg + 0) * 66 + lane];
            float f1 = s_F[(cg + 1) * 66 + lane];
            float f2 = s_F[(cg + 2) * 66 + lane];
            float f3 = s_F[(cg + 3) * 66 + lane];
            FMA8_STEP(w0n, w1n, w2n, w3n, w4n, w5n, w6n, w7n, cg, f0, f1, f2, f3)
        }
        float fd = s_F[64 * 66 + lane];
        a0 += w0n[64] * fd; a1 += w1n[64] * fd; a2 += w2n[64] * fd; a3 += w3n[64] * fd;
        a4 += w4n[64] * fd; a5 += w5n[64] * fd; a6 += w6n[64] * fd; a7 += w7n[64] * fd;
        if (lane < tl) {
            size_t col = (size_t)s_vox[lane];
            STORE8(col)
        }
        __syncthreads();
    }

    // ---- count==2 tiles: two passes over the 65-row F tile ----
    for (int t0 = 0; t0 < n2; t0 += 64) {
        int tl = min(64, n2 - t0);
        for (int e = wv; e < tl; e += NWV) {         // pass A gather: cams {0,3,4}
            float4 r0 = s_rec2[2 * (t0 + e) + 0];
            float4 r1 = s_rec2[2 * (t0 + e) + 1];
            int m0 = __float_as_int(r0.w), m1 = __float_as_int(r1.w);
            int ca = m0 & 7, cb = m1 & 7;
            float fg = 0.0f, dd = 0.0f;
            if (!(ca == 1 || ca == 2 || ca == 5)) {
                fg += gather_bilin(fsrc, useT, lane, ca, r0.x, r0.y);
                dd += r0.z / 100.0f;
            }
            if (!(cb == 1 || cb == 2 || cb == 5)) {
                fg += gather_bilin(fsrc, useT, lane, cb, r1.x, r1.y);
                dd += r1.z / 100.0f;
            }
            s_F[lane * 66 + e] = fg;
            if (lane == 0) { s_F[64 * 66 + e] = dd; s_vox[e] = m0 >> 3; }
        }
        __syncthreads();
        float a0 = bo[obase + 0], a1 = bo[obase + 1], a2 = bo[obase + 2], a3 = bo[obase + 3];
        float a4 = bo[obase + 4], a5 = bo[obase + 5], a6 = bo[obase + 6], a7 = bo[obase + 7];
        for (int cg = 0; cg < 64; cg += 4) {         // pass A compute: cols 0..64
            float f0 = s_F[(cg + 0) * 66 + lane];
            float f1 = s_F[(cg + 1) * 66 + lane];
            float f2 = s_F[(cg + 2) * 66 + lane];
            float f3 = s_F[(cg + 3) * 66 + lane];
            FMA8_STEP(w0o, w1o, w2o, w3o, w4o, w5o, w6o, w7o, cg, f0, f1, f2, f3)
        }
        {
            float fd = s_F[64 * 66 + lane];
            a0 += w0o[64] * fd; a1 += w1o[64] * fd; a2 += w2o[64] * fd; a3 += w3o[64] * fd;
            a4 += w4o[64] * fd; a5 += w5o[64] * fd; a6 += w6o[64] * fd; a7 += w7o[64] * fd;
        }
        __syncthreads();
        for (int e = wv; e < tl; e += NWV) {         // pass B gather: cams {1,2,5}
            float4 r0 = s_rec2[2 * (t0 + e) + 0];
            float4 r1 = s_rec2[2 * (t0 + e) + 1];
            int m0 = __float_as_int(r0.w), m1 = __float_as_int(r1.w);
            int ca = m0 & 7, cb = m1 & 7;
            float fg = 0.0f, dd = 0.0f;
            if (ca == 1 || ca == 2 || ca == 5) {
                fg += gather_bilin(fsrc, useT, lane, ca, r0.x, r0.y);
                dd += r0.z / 100.0f;
            }
            if (cb == 1 || cb == 2 || cb == 5) {
                fg += gather_bilin(fsrc, useT, lane, cb, r1.x, r1.y);
                dd += r1.z / 100.0f;
            }
            s_F[lane * 66 + e] = fg;
            if (lane == 0) s_F[64 * 66 + e] = dd;
        }
        __syncthreads();
        for (int cg = 0; cg < 64; cg += 4) {         // pass B compute: cols 65..129
            float f0 = s_F[(cg + 0) * 66 + lane];
            float f1 = s_F[(cg + 1) * 66 + lane];
            float f2 = s_F[(cg + 2) * 66 + lane];
            float f3 = s_F[(cg + 3) * 66 + lane];
            int cgo = cg + 65;
            FMA8_STEP(w0o, w1o, w2o, w3o, w4o, w5o, w6o, w7o, cgo, f0, f1, f2, f3)
        }
        {
            float fd = s_F[64 * 66 + lane];
            a0 += w0o[129] * fd; a1 += w1o[129] * fd; a2 += w2o[129] * fd; a3 += w3o[129] * fd;
            a4 += w4o[129] * fd; a5 += w5o[129] * fd; a6 += w6o[129] * fd; a7 += w7o[129] * fd;
        }
        if (lane < tl) {
            size_t col = (size_t)s_vox[lane];
            STORE8(col)
        }
        __syncthreads();
    }
}

extern "C" void kernel_launch(void* const* d_in, const int* in_sizes, int n_in,
                              void* d_out, int out_size, void* d_ws, size_t ws_size,
                              hipStream_t stream) {
    const float* feats = (const float*)d_in[0];
    const float* mask  = (const float*)d_in[1];
    const float* Kg    = (const float*)d_in[2];
    const float* ext   = (const float*)d_in[3];
    const float* wno   = (const float*)d_in[4];
    const float* bno   = (const float*)d_in[5];
    const float* wo    = (const float*)d_in[6];
    const float* bo    = (const float*)d_in[7];
    float* outp = (float*)d_out;
    float* featT = (float*)d_ws;

    int useT = (ws_size >= (size_t)FEATT_BYTES) ? 1 : 0;
    if (useT) {
        transpose_feats<<<NC * 220, 256, 0, stream>>>(feats, featT);
    }
    int nblk = (NVOX + VB - 1) / VB;                 // 1563
    vox_fused<<<nblk, NTH, 0, stream>>>(feats, featT, mask, Kg, ext,
                                        wno, bno, wo, bo, outp, useT);
}